// Round 1
// baseline (48.154 us; speedup 1.0000x reference)
//
#include <hip/hip_runtime.h>
#include <math.h>

#define BS 256
#define NB 2048
#define NWAVES (BS / 64)

// ---------- wave / block reduction helpers ----------
__device__ inline double wred_sum(double v) {
#pragma unroll
    for (int o = 32; o > 0; o >>= 1) v += __shfl_down(v, o, 64);
    return v;
}
__device__ inline float wred_min(float v) {
#pragma unroll
    for (int o = 32; o > 0; o >>= 1) v = fminf(v, __shfl_down(v, o, 64));
    return v;
}
__device__ inline float wred_max(float v) {
#pragma unroll
    for (int o = 32; o > 0; o >>= 1) v = fmaxf(v, __shfl_down(v, o, 64));
    return v;
}

// ---------- pass 1: per-block {sum, sumsq, min, max} over targets ----------
__global__ void __launch_bounds__(BS) k_stats(
        const float* __restrict__ t, int n,
        double* __restrict__ bsum, double* __restrict__ bss,
        float* __restrict__ bmn, float* __restrict__ bmx) {
    int tid = blockIdx.x * BS + threadIdx.x;
    int stride = gridDim.x * BS;
    int n4 = n >> 2;
    const float4* t4 = (const float4*)t;

    double s = 0.0, ss = 0.0;
    float mn = 3.4e38f, mx = -3.4e38f;
    for (int i = tid; i < n4; i += stride) {
        float4 v = t4[i];
        mn = fminf(mn, fminf(fminf(v.x, v.y), fminf(v.z, v.w)));
        mx = fmaxf(mx, fmaxf(fmaxf(v.x, v.y), fmaxf(v.z, v.w)));
        s += (double)v.x + (double)v.y + (double)v.z + (double)v.w;
        ss += (double)v.x * v.x + (double)v.y * v.y
            + (double)v.z * v.z + (double)v.w * v.w;
    }
    if (tid == 0) {  // scalar tail (n % 4), robustness only
        for (int i = (n4 << 2); i < n; i++) {
            float v = t[i];
            mn = fminf(mn, v); mx = fmaxf(mx, v);
            s += v; ss += (double)v * v;
        }
    }

    s = wred_sum(s); ss = wred_sum(ss); mn = wred_min(mn); mx = wred_max(mx);

    __shared__ double sh_s[NWAVES], sh_ss[NWAVES];
    __shared__ float sh_mn[NWAVES], sh_mx[NWAVES];
    int wid = threadIdx.x >> 6, lane = threadIdx.x & 63;
    if (lane == 0) { sh_s[wid] = s; sh_ss[wid] = ss; sh_mn[wid] = mn; sh_mx[wid] = mx; }
    __syncthreads();
    if (threadIdx.x == 0) {
        double S = sh_s[0], SS = sh_ss[0];
        float MN = sh_mn[0], MX = sh_mx[0];
        for (int i = 1; i < NWAVES; i++) {
            S += sh_s[i]; SS += sh_ss[i];
            MN = fminf(MN, sh_mn[i]); MX = fmaxf(MX, sh_mx[i]);
        }
        bsum[blockIdx.x] = S; bss[blockIdx.x] = SS;
        bmn[blockIdx.x] = MN; bmx[blockIdx.x] = MX;
    }
}

// ---------- pass 2: fold block partials -> piecewise-weight constants ----------
__global__ void __launch_bounds__(BS) k_finalize_stats(
        const double* __restrict__ bsum, const double* __restrict__ bss,
        const float* __restrict__ bmn, const float* __restrict__ bmx,
        int nb, long long n, float* __restrict__ stats) {
    double s = 0.0, ss = 0.0;
    float mn = 3.4e38f, mx = -3.4e38f;
    for (int i = threadIdx.x; i < nb; i += BS) {
        s += bsum[i]; ss += bss[i];
        mn = fminf(mn, bmn[i]); mx = fmaxf(mx, bmx[i]);
    }
    s = wred_sum(s); ss = wred_sum(ss); mn = wred_min(mn); mx = wred_max(mx);

    __shared__ double sh_s[NWAVES], sh_ss[NWAVES];
    __shared__ float sh_mn[NWAVES], sh_mx[NWAVES];
    int wid = threadIdx.x >> 6, lane = threadIdx.x & 63;
    if (lane == 0) { sh_s[wid] = s; sh_ss[wid] = ss; sh_mn[wid] = mn; sh_mx[wid] = mx; }
    __syncthreads();
    if (threadIdx.x == 0) {
        double S = sh_s[0], SS = sh_ss[0];
        float MN = sh_mn[0], MX = sh_mx[0];
        for (int i = 1; i < NWAVES; i++) {
            S += sh_s[i]; SS += sh_ss[i];
            MN = fminf(MN, sh_mn[i]); MX = fmaxf(MX, sh_mx[i]);
        }
        double dn = (double)n;
        double mean = S / dn;
        double var = (SS - S * S / dn) / (dn - 1.0);   // ddof=1
        double sd = sqrt(var);
        float gmin = MN, gmax = MX;
        float m1 = (float)(mean + sd);
        float m2 = (float)(mean + 3.0 * sd);
        stats[0] = gmin;
        stats[1] = m1;
        stats[2] = m2;
        stats[3] = gmax;
        stats[4] = 0.2f / (m1 - gmin);   // low slope
        stats[5] = 0.5f / (m2 - m1);     // mid slope
        stats[6] = 0.3f / (gmax - m2);   // high slope
    }
}

// ---------- pass 3: weighted L1 partial sums ----------
__device__ inline float welem(float g, float x, float gmin, float m1, float m2,
                              float sl, float sm, float shv) {
    float w = (g <= m1) ? (g - gmin) * sl
            : (g <= m2) ? (g - m1) * sm + 0.2f
                        : (g - m2) * shv + 0.7f;
    return fabsf(g - x) * w;
}

__global__ void __launch_bounds__(BS) k_loss(
        const float* __restrict__ x, const float* __restrict__ t, int n,
        const float* __restrict__ stats, double* __restrict__ bsum) {
    float gmin = stats[0], m1 = stats[1], m2 = stats[2];
    float sl = stats[4], sm = stats[5], shv = stats[6];
    int tid = blockIdx.x * BS + threadIdx.x;
    int stride = gridDim.x * BS;
    int n4 = n >> 2;
    const float4* x4 = (const float4*)x;
    const float4* t4 = (const float4*)t;

    double acc = 0.0;
    for (int i = tid; i < n4; i += stride) {
        float4 tv = t4[i], xv = x4[i];
        float e0 = welem(tv.x, xv.x, gmin, m1, m2, sl, sm, shv);
        float e1 = welem(tv.y, xv.y, gmin, m1, m2, sl, sm, shv);
        float e2 = welem(tv.z, xv.z, gmin, m1, m2, sl, sm, shv);
        float e3 = welem(tv.w, xv.w, gmin, m1, m2, sl, sm, shv);
        acc += (double)e0 + (double)e1 + (double)e2 + (double)e3;
    }
    if (tid == 0) {  // scalar tail
        for (int i = (n4 << 2); i < n; i++)
            acc += (double)welem(t[i], x[i], gmin, m1, m2, sl, sm, shv);
    }

    acc = wred_sum(acc);
    __shared__ double sh_s[NWAVES];
    int wid = threadIdx.x >> 6, lane = threadIdx.x & 63;
    if (lane == 0) sh_s[wid] = acc;
    __syncthreads();
    if (threadIdx.x == 0) {
        double S = sh_s[0];
        for (int i = 1; i < NWAVES; i++) S += sh_s[i];
        bsum[blockIdx.x] = S;
    }
}

// ---------- pass 4: final mean ----------
__global__ void __launch_bounds__(BS) k_final(
        const double* __restrict__ bsum, int nb, long long n,
        float* __restrict__ out) {
    double s = 0.0;
    for (int i = threadIdx.x; i < nb; i += BS) s += bsum[i];
    s = wred_sum(s);
    __shared__ double sh_s[NWAVES];
    int wid = threadIdx.x >> 6, lane = threadIdx.x & 63;
    if (lane == 0) sh_s[wid] = s;
    __syncthreads();
    if (threadIdx.x == 0) {
        double S = sh_s[0];
        for (int i = 1; i < NWAVES; i++) S += sh_s[i];
        out[0] = (float)(S / (double)n);
    }
}

extern "C" void kernel_launch(void* const* d_in, const int* in_sizes, int n_in,
                              void* d_out, int out_size, void* d_ws, size_t ws_size,
                              hipStream_t stream) {
    const float* inp = (const float*)d_in[0];
    const float* tgt = (const float*)d_in[1];
    int n = in_sizes[0];

    // workspace layout (bytes):
    //   [0,      16384) double sum1[NB]
    //   [16384,  32768) double ss1[NB]
    //   [32768,  40960) float  mn1[NB]
    //   [40960,  49152) float  mx1[NB]
    //   [49152,  49216) float  stats[8] (padded)
    //   [49216,  65600) double sum2[NB]
    char* ws = (char*)d_ws;
    double* sum1 = (double*)(ws);
    double* ss1  = (double*)(ws + 16384);
    float*  mn1  = (float*)(ws + 32768);
    float*  mx1  = (float*)(ws + 40960);
    float*  stats = (float*)(ws + 49152);
    double* sum2 = (double*)(ws + 49216);

    k_stats<<<NB, BS, 0, stream>>>(tgt, n, sum1, ss1, mn1, mx1);
    k_finalize_stats<<<1, BS, 0, stream>>>(sum1, ss1, mn1, mx1, NB, (long long)n, stats);
    k_loss<<<NB, BS, 0, stream>>>(inp, tgt, n, stats, sum2);
    k_final<<<1, BS, 0, stream>>>(sum2, NB, (long long)n, (float*)d_out);
}